// Round 20
// baseline (2739.646 us; speedup 1.0000x reference)
//
#include <hip/hip_runtime.h>
#include <math.h>

// Shapes (fixed): B=16, Cin=3, C=64, H=W=384, E=768, P=16, G=24, K_sel=64
// conv2 v5.2 (best, 56us): 144 px/block -> 1024 blocks = exactly 2.0 dispatch rounds
//   at 2 blocks/CU; LDS padded to 54KB. global_load_lds(16) + both-sides XOR swizzle.
// conv1 v4: 64 px/block, 512 thr (same per-thread math as r6 -> bit-identical f1);
//   halves block count + weight reloads, 8 waves/block latency cover.
// gemmcd one-launch coarse+detail (z=8); prep/cvt3/reduceboth merges.
// coarse: M=576,N=768,K=16384  detail(sel): M=256,N=768,K=4096  merge: M=1024,N=768,K=3072

__device__ __forceinline__ float gelu_f(float v){
    return 0.5f*v*(1.0f + erff(v*0.70710678118654752440f));
}
__device__ __forceinline__ unsigned short f2bf(float v){
    unsigned u = __float_as_uint(v);
    return (unsigned short)((u + 0x7FFFu + ((u>>16)&1u)) >> 16);   // RNE
}
__device__ __forceinline__ float bf2f(unsigned short h){
    return __uint_as_float(((unsigned)h)<<16);
}
__device__ __forceinline__ void split2(float v, unsigned short& hi, unsigned short& lo){
    hi = f2bf(v);
    lo = f2bf(v - bf2f(hi));
}

typedef short bf16x8 __attribute__((ext_vector_type(8)));
typedef float f32x4  __attribute__((ext_vector_type(4)));

// ---- merged prep: bid 0 = BN scale/shift, bid 1..144 = conv2 weight split-2,
// bid 145..193 = f1 border zero
__global__ __launch_bounds__(256) void prep_k(
        const float* g1,const float* b1,const float* m1,const float* v1,
        const float* g2,const float* b2,const float* m2,const float* v2,
        const float* __restrict__ w2,
        float* outp, unsigned short* __restrict__ bhi, unsigned short* __restrict__ blo,
        unsigned short* __restrict__ f1hi, unsigned short* __restrict__ f1lo){
    int bid = blockIdx.x;
    if (bid == 0){
        int t = threadIdx.x;
        if (t < 64){
            float s = g1[t]/sqrtf(v1[t]+1e-5f);
            outp[t] = s; outp[64+t] = b1[t]-m1[t]*s;
            float s2 = g2[t]/sqrtf(v2[t]+1e-5f);
            outp[128+t] = s2; outp[192+t] = b2[t]-m2[t]*s2;
        }
    } else if (bid <= 144){
        int idx = (bid-1)*256 + threadIdx.x;
        if (idx < 36864){
            int n = idx/576, kp = idx - n*576;
            int t = kp>>6, ci = kp&63; int kh = t/3, kw = t - kh*3;
            float v = w2[((n*64+ci)*3+kh)*3+kw];
            unsigned short hi,lo; split2(v,hi,lo);
            bhi[n*576+kp]=hi; blo[n*576+kp]=lo;
        }
    } else {
        int idx = (bid-145)*256 + threadIdx.x;
        if (idx < 1540*8){
            int pi = idx>>3, c8 = (idx&7)*8;
            int p;
            if (pi < 386)       p = pi;
            else if (pi < 772)  p = 385*386 + (pi-386);
            else if (pi < 1156) p = (pi-772+1)*386;
            else                p = (pi-1156+1)*386 + 385;
            float4 z = {0.f,0.f,0.f,0.f};
            *(float4*)(f1hi + (size_t)p*64 + c8) = z;
            *(float4*)(f1lo + (size_t)p*64 + c8) = z;
        }
    }
}

// ---- all 3 weight tensors f32 -> bf16 in one launch
__global__ __launch_bounds__(256) void cvt3_k(const float* __restrict__ cw,
                                              const float* __restrict__ dw,
                                              const float* __restrict__ mw,
                                              unsigned short* __restrict__ wc,
                                              unsigned short* __restrict__ wd,
                                              unsigned short* __restrict__ wm){
    int i = blockIdx.x*256 + threadIdx.x;
    if (i < 12582912){
        wc[i] = f2bf(cw[i]);
    } else if (i < 15728640){
        int j = i - 12582912; wd[j] = f2bf(dw[j]);
    } else if (i < 18087936){
        int j = i - 15728640; wm[j] = f2bf(mw[j]);
    }
}

// ---- conv1 v4: 3->64 3x3 SAME + BN + GELU; padded (386x386) NHWC split-2 bf16.
// 64 px/block, 512 thr; per-thread math identical to r6 (1 px x 8 ch, same j order)
// -> bit-identical f1. Halo staging [ci][kh][66].
__global__ __launch_bounds__(512) void conv1_k(const float* __restrict__ x,
                                               const float* __restrict__ w,
                                               const float* __restrict__ bnp,
                                               unsigned short* __restrict__ f1hi,
                                               unsigned short* __restrict__ f1lo){
    __shared__ float ws[64*27];
    __shared__ float xr[9*66];
    __shared__ float s1[64], sh1[64];
    int tid = threadIdx.x;
    for (int i=tid;i<1728;i+=512) ws[i] = w[i];
    if (tid < 64){ s1[tid] = bnp[tid]; sh1[tid] = bnp[64+tid]; }
    int bid = blockIdx.x;
    int swb = (bid&7)*288 + (bid>>3);      // 2304 blocks, XCD-aligned with conv2
    int p0 = swb*64;
    int h0 = p0/384, x0 = p0 - h0*384;     // 64 | 384 -> row-uniform block
    for (int t=tid; t<594; t+=512){
        int ci = t/198, rem = t - ci*198;
        int kh = rem/66, col = rem - kh*66;
        int y = h0+kh-1, xx = x0+col-1;
        float v = 0.f;
        if ((unsigned)y<384u && (unsigned)xx<384u)
            v = x[ci*147456 + y*384 + xx];
        xr[(ci*3+kh)*66 + col] = v;
    }
    __syncthreads();
    int px = tid>>3, cg = tid&7;
    float a[8];
    #pragma unroll
    for (int u=0;u<8;u++) a[u]=0.f;
    #pragma unroll
    for (int ci=0;ci<3;ci++)
        #pragma unroll
        for (int kh=0;kh<3;kh++)
            #pragma unroll
            for (int kw=0;kw<3;kw++){
                const int j = (ci*3+kh)*3+kw;            // same j order as before
                float xv = xr[(ci*3+kh)*66 + px + kw];
                #pragma unroll
                for (int u=0;u<8;u++) a[u] += xv*ws[(cg*8+u)*27+j];
            }
    unsigned short hs[8], ls[8];
    #pragma unroll
    for (int u=0;u<8;u++){
        int co = cg*8+u;
        float v = gelu_f(a[u]*s1[co] + sh1[co]);
        split2(v, hs[u], ls[u]);
    }
    size_t off = ((size_t)(h0+1)*386 + (x0+px+1))*64 + cg*8;
    *(float4*)(f1hi + off) = *(float4*)hs;
    *(float4*)(f1lo + off) = *(float4*)ls;
}

// ---- conv2 v5.2: 144 px/block, 1024 blocks = 2.0 rounds at 2 blocks/CU.
// LDS-staged via global_load_lds, 2 barriers/tap, both-sides XOR swizzle.
// LDS padded (BlL +1024 shorts) to 54KB so exactly 2 blocks/CU. One image.
// Fused epilogue: Ac16 bf16 + per-(cell,row,ch) {sum,sumsq} partials.
__global__ __launch_bounds__(192) void conv2_mfma_k(
        const unsigned short* __restrict__ f1hi, const unsigned short* __restrict__ f1lo,
        const unsigned short* __restrict__ bhi,  const unsigned short* __restrict__ blo,
        const float* __restrict__ bnsc, const float* __restrict__ bnsh,
        unsigned short* __restrict__ Ac, float* __restrict__ parts){
    __shared__ __align__(16) unsigned short AhL[144*64], AlL[144*64];
    __shared__ __align__(16) unsigned short BhL[64*64],  BlL[64*64 + 1024]; // pad pins 2/CU
    const int tid = threadIdx.x;
    const int bid = blockIdx.x;
    const int swz = (bid&7)*128 + (bid>>3);    // 1024 blocks, XCD-aligned
    const int bm = swz*144;                    // 144 | 16-aligned; may cross row
    const int wv = tid>>6, lane = tid&63, lm = lane&15, q = lane>>4;

    // staging sources (per-thread constants; tap adds an offset). Per-granule (y,x).
    int aSrc[6];
    #pragma unroll
    for (int i=0;i<6;i++){
        int g = tid + i*192;                   // 0..1151 granules
        int pr = g>>3, p8 = g&7;
        int p = bm + pr;
        int y = p/384, x = p - y*384;
        aSrc[i] = (y*386 + x)*64 + ((p8 ^ (pr&7))<<3);   // pad absorbs -1
    }
    int bSrc[3];
    #pragma unroll
    for (int i=0;i<3;i++){
        int ch = tid + i*192;
        int n = ch>>3, p8 = ch&7;
        bSrc[i] = n*576 + ((p8 ^ (n&7))<<3);
    }
    // ds_read byte addrs (swizzled), per-thread constants
    int aRd[3][2], bRd[4][2];
    #pragma unroll
    for (int mi=0;mi<3;mi++){
        int r = wv*48 + mi*16 + lm;            // 0..143
        #pragma unroll
        for (int h=0;h<2;h++)
            aRd[mi][h] = r*128 + (((h*4+q) ^ (r&7))<<4);
    }
    #pragma unroll
    for (int nj=0;nj<4;nj++){
        int r = nj*16 + lm;
        #pragma unroll
        for (int h=0;h<2;h++)
            bRd[nj][h] = r*128 + (((h*4+q) ^ (r&7))<<4);
    }

    f32x4 acc[3][4];
    #pragma unroll
    for (int i=0;i<3;i++)
        #pragma unroll
        for (int j=0;j<4;j++) acc[i][j] = (f32x4){0.f,0.f,0.f,0.f};

    for (int t9=0; t9<9; t9++){
        const int kh = t9/3, kw = t9 - kh*3;
        const int aoff = (kh*386 + kw)*64;
        const int boff = t9*64;
        #pragma unroll
        for (int i=0;i<6;i++){
            __builtin_amdgcn_global_load_lds(f1hi + aSrc[i] + aoff, &AhL[(tid+i*192)*8], 16, 0, 0);
            __builtin_amdgcn_global_load_lds(f1lo + aSrc[i] + aoff, &AlL[(tid+i*192)*8], 16, 0, 0);
        }
        #pragma unroll
        for (int i=0;i<3;i++){
            int ch = tid + i*192;
            if (ch < 512){   // wave-uniform: i=2 skips wave 2 entirely
                __builtin_amdgcn_global_load_lds(bhi + bSrc[i] + boff, &BhL[ch*8], 16, 0, 0);
                __builtin_amdgcn_global_load_lds(blo + bSrc[i] + boff, &BlL[ch*8], 16, 0, 0);
            }
        }
        __syncthreads();
        #pragma unroll
        for (int h=0; h<2; h++){
            bf16x8 ah[3], al[3], bh8[4], bl8[4];
            #pragma unroll
            for (int mi=0;mi<3;mi++){
                ah[mi] = *(const bf16x8*)((const char*)AhL + aRd[mi][h]);
                al[mi] = *(const bf16x8*)((const char*)AlL + aRd[mi][h]);
            }
            #pragma unroll
            for (int nj=0;nj<4;nj++){
                bh8[nj] = *(const bf16x8*)((const char*)BhL + bRd[nj][h]);
                bl8[nj] = *(const bf16x8*)((const char*)BlL + bRd[nj][h]);
            }
            #pragma unroll
            for (int mi=0;mi<3;mi++)
                #pragma unroll
                for (int nj=0;nj<4;nj++){
                    acc[mi][nj] = __builtin_amdgcn_mfma_f32_16x16x32_bf16(ah[mi], bh8[nj], acc[mi][nj], 0,0,0);
                    acc[mi][nj] = __builtin_amdgcn_mfma_f32_16x16x32_bf16(al[mi], bh8[nj], acc[mi][nj], 0,0,0);
                    acc[mi][nj] = __builtin_amdgcn_mfma_f32_16x16x32_bf16(ah[mi], bl8[nj], acc[mi][nj], 0,0,0);
                }
        }
        __syncthreads();
    }

    // ---- fused epilogue: gelu -> Ac16 bf16 + per-cell-row {sum,sumsq} partials
    // 16-px groups are 16-aligned and never cross a row (16 | 384); per-mi (y,x).
    #pragma unroll
    for (int mi=0;mi<3;mi++){
        const int p0m = bm + wv*48 + mi*16;
        const int ym = p0m/384, xm = p0m - ym*384;
        const int cell = (ym>>4)*24 + (xm>>4);
        const int py = ym&15;
        unsigned short* acb = Ac + (size_t)cell*16384;
        float* pp = parts + (size_t)(cell*16 + py)*128;   // 64 ch * 2 floats
        #pragma unroll
        for (int nj=0;nj<4;nj++){
            const int n = nj*16 + lm;
            const float sc = bnsc[n], sh = bnsh[n];
            float g0 = gelu_f(acc[mi][nj][0]*sc + sh);
            float g1 = gelu_f(acc[mi][nj][1]*sc + sh);
            float g2 = gelu_f(acc[mi][nj][2]*sc + sh);
            float g3 = gelu_f(acc[mi][nj][3]*sc + sh);
            // Ac16: k = n*256 + py*16 + (q*4 + r), 8B store
            unsigned int u0 = (unsigned)f2bf(g0) | ((unsigned)f2bf(g1)<<16);
            unsigned int u1 = (unsigned)f2bf(g2) | ((unsigned)f2bf(g3)<<16);
            uint2 uu; uu.x = u0; uu.y = u1;
            *(uint2*)(acb + (size_t)n*256 + py*16 + q*4) = uu;
            // partial sum/sumsq over this 16-px cell-row slice
            float s  = ((g0+g1)+g2)+g3;
            float ss = ((g0*g0+g1*g1)+g2*g2)+g3*g3;
            s  += __shfl_xor(s,16);  s  += __shfl_xor(s,32);
            ss += __shfl_xor(ss,16); ss += __shfl_xor(ss,32);
            if (q==0){
                float2 v; v.x = s; v.y = ss;
                *(float2*)(pp + n*2) = v;
            }
        }
    }
}

// ---- per-cell score from partials: var = E[x^2]-E[x]^2 per ch, mean over ch
__global__ __launch_bounds__(64) void score_k(const float* __restrict__ parts,
                                              float* __restrict__ scores){
    const int cell = blockIdx.x;       // 0..575
    const int n = threadIdx.x;         // channel
    float s = 0.f, ss = 0.f;
    #pragma unroll
    for (int py=0;py<16;py++){
        float2 v = *(const float2*)(parts + (size_t)(cell*16+py)*128 + n*2);
        s += v.x; ss += v.y;
    }
    float mean = s*(1.f/256.f);
    float var  = ss*(1.f/256.f) - mean*mean;
    var += __shfl_down(var,32); var += __shfl_down(var,16);
    var += __shfl_down(var,8);  var += __shfl_down(var,4);
    var += __shfl_down(var,2);  var += __shfl_down(var,1);
    if (n==0) scores[cell] = var*(1.f/64.f);
}

// ---- gemm body (r6-exact math): tile M=64 x N=128, 256 thr (4 waves), K-split z.
// Staging via global_load_lds(16); linear 128B LDS rows; both-sides XOR swizzle.
// LDS tile is passed in (single allocation in the calling kernel).
template<int MODE, int KL, int MT>
__device__ __forceinline__ void gemm_body(const unsigned short* __restrict__ A,
                                          const unsigned short* __restrict__ W,
                                          const int* __restrict__ topk,
                                          float* __restrict__ part,
                                          unsigned short* As, unsigned short* Bs,
                                          int nt, int mt, int z){
    constexpr int KT = (MODE==0)?16384:(MODE==1)?4096:3072;   // W row length
    const int tid = threadIdx.x;
    const int m0 = mt*64, n0 = nt*128;
    const int wv = tid>>6, lane = tid&63;
    const int lm = lane&15, q = lane>>4;

    const int srow = tid>>3, sslot = tid&7;
    const int sx = (sslot ^ (srow&7))*8;          // logical k offset (shorts)
    size_t aSb[2];
    #pragma unroll
    for (int it=0;it<2;it++){
        int row = srow + it*32;                   // (row&7) == (srow&7)
        if (MODE==1){
            int t = m0 + row; int sel = t>>2, dd = t&3;
            int cell = topk[sel];
            aSb[it] = (size_t)cell*16384 + (dd>>1)*128 + (dd&1)*8 + sx*2;
        } else {
            aSb[it] = (size_t)(m0+row)*KT + sx;
        }
    }
    size_t bSb[4];
    #pragma unroll
    for (int it=0;it<4;it++)
        bSb[it] = (size_t)(n0 + srow + it*32)*KT + sx;

    int aRd[4][2], bRd[2][2];
    #pragma unroll
    for (int mi=0;mi<4;mi++){
        int r = mi*16 + lm;
        #pragma unroll
        for (int h=0;h<2;h++)
            aRd[mi][h] = r*128 + (((h*4+q) ^ (r&7))<<4);
    }
    #pragma unroll
    for (int nj=0;nj<2;nj++){
        int r = wv*32 + nj*16 + lm;
        #pragma unroll
        for (int h=0;h<2;h++)
            bRd[nj][h] = r*128 + (((h*4+q) ^ (r&7))<<4);
    }

    f32x4 acc[4][2];
    #pragma unroll
    for (int i=0;i<4;i++)
        #pragma unroll
        for (int j=0;j<2;j++)
            acc[i][j] = (f32x4){0.f,0.f,0.f,0.f};

    const int kb0 = z*KL;
    for (int kb = kb0; kb < kb0+KL; kb += 64){
        #pragma unroll
        for (int it=0;it<2;it++){
            const unsigned short* src = (MODE==1) ? (A + aSb[it] + (size_t)(kb>>6)*256)
                                                  : (A + aSb[it] + kb);
            __builtin_amdgcn_global_load_lds(src, &As[(tid + it*256)*8], 16, 0, 0);
        }
        #pragma unroll
        for (int it=0;it<4;it++)
            __builtin_amdgcn_global_load_lds(W + bSb[it] + kb, &Bs[(tid + it*256)*8], 16, 0, 0);
        __syncthreads();
        #pragma unroll
        for (int h=0;h<2;h++){
            bf16x8 af[4], bb[2];
            #pragma unroll
            for (int mi=0;mi<4;mi++) af[mi] = *(const bf16x8*)((const char*)As + aRd[mi][h]);
            #pragma unroll
            for (int nj=0;nj<2;nj++) bb[nj] = *(const bf16x8*)((const char*)Bs + bRd[nj][h]);
            #pragma unroll
            for (int mi=0;mi<4;mi++)
                #pragma unroll
                for (int nj=0;nj<2;nj++)
                    acc[mi][nj] = __builtin_amdgcn_mfma_f32_16x16x32_bf16(af[mi], bb[nj], acc[mi][nj], 0,0,0);
        }
        __syncthreads();
    }

    float* pz = part + (size_t)z*MT*768;
    #pragma unroll
    for (int mi=0;mi<4;mi++)
        #pragma unroll
        for (int nj=0;nj<2;nj++)
            #pragma unroll
            for (int r=0;r<4;r++){
                int m = m0 + mi*16 + q*4 + r;
                int n = n0 + wv*32 + nj*16 + lm;
                pz[m*768 + n] = acc[mi][nj][r];
            }
}

// ---- coarse + detail GEMM in one launch: grid (6, 13, 8); y<9 coarse, else detail
__global__ __launch_bounds__(256) void gemmcd_k(const unsigned short* __restrict__ Ac,
                                                const unsigned short* __restrict__ Wc,
                                                const unsigned short* __restrict__ Wd,
                                                const int* __restrict__ topk,
                                                float* __restrict__ partC,
                                                float* __restrict__ partD){
    __shared__ __align__(16) unsigned short As[64*64];
    __shared__ __align__(16) unsigned short Bs[128*64];
    const int mt = blockIdx.y;
    if (mt < 9)
        gemm_body<0,2048,576>(Ac, Wc, nullptr, partC, As, Bs, blockIdx.x, mt, blockIdx.z);
    else
        gemm_body<1,512,256>(Ac, Wd, topk, partD, As, Bs, blockIdx.x, mt-9, blockIdx.z);
}

// ---- merge GEMM (unchanged structure)
__global__ __launch_bounds__(256) void gemmm_k(const unsigned short* __restrict__ A,
                                               const unsigned short* __restrict__ W,
                                               float* __restrict__ part){
    __shared__ __align__(16) unsigned short As[64*64];
    __shared__ __align__(16) unsigned short Bs[128*64];
    gemm_body<2,768,1024>(A, W, nullptr, part, As, Bs, blockIdx.x, blockIdx.y, blockIdx.z);
}

// ---- merged per-batch reduction: coarse (f32 out) + detail (bf16 out), both z=8
__global__ __launch_bounds__(256) void reduceboth_k(const float* __restrict__ partC,
                                                    const float* __restrict__ partD,
                                                    const float* __restrict__ cb,
                                                    const float* __restrict__ db,
                                                    float* __restrict__ outC,
                                                    unsigned short* __restrict__ outD){
    int bid = blockIdx.x;
    if (bid < 1728){
        int idx = bid*256 + threadIdx.x;          // 0..442367
        int col = idx % 768;
        float s = cb[col];
        #pragma unroll
        for (int i=0;i<8;i++) s += partC[(size_t)i*442368 + idx];
        outC[idx] = s;
    } else {
        int idx = (bid-1728)*256 + threadIdx.x;   // 0..196607
        int col = idx % 768;
        float s = db[col];
        #pragma unroll
        for (int i=0;i<8;i++) s += partD[(size_t)i*196608 + idx];
        outD[idx] = f2bf(s);
    }
}

// ---- final merge reduction: sum K-split partials + bias -> f32
__global__ __launch_bounds__(256) void reduce_k(const float* __restrict__ partials,
                                                const float* __restrict__ bias,
                                                float* __restrict__ outp,
                                                int MTOT, int NSPLIT){
    int idx = blockIdx.x*256 + threadIdx.x;
    int col = idx % 768;
    float s = bias[col];
    for (int i=0;i<NSPLIT;i++) s += partials[(size_t)i*MTOT*768 + idx];
    outp[idx] = s;
}

// ---- top-64 of 576 via rank counting; jax tie-break (lower idx first), one shot
__global__ __launch_bounds__(576) void topk_k(const float* __restrict__ scores,
                                              int* __restrict__ topk,
                                              float* __restrict__ outf){
    __shared__ float s[576];
    int t = threadIdx.x;
    s[t] = scores[t];
    __syncthreads();
    float v = s[t];
    int cnt = 0;
    for (int j=0;j<576;j++){
        float u = s[j];
        cnt += (u > v) || (u == v && j < t);
    }
    if (cnt < 64){ topk[cnt] = t; outf[cnt] = (float)t; }
}

extern "C" void kernel_launch(void* const* d_in, const int* in_sizes, int n_in,
                              void* d_out, int out_size, void* d_ws, size_t ws_size,
                              hipStream_t stream){
    const float* x       = (const float*)d_in[0];
    const float* conv1_w = (const float*)d_in[1];
    const float* bn1_g   = (const float*)d_in[2];
    const float* bn1_b   = (const float*)d_in[3];
    const float* bn1_m   = (const float*)d_in[4];
    const float* bn1_v   = (const float*)d_in[5];
    const float* conv2_w = (const float*)d_in[6];
    const float* bn2_g   = (const float*)d_in[7];
    const float* bn2_b   = (const float*)d_in[8];
    const float* bn2_m   = (const float*)d_in[9];
    const float* bn2_v   = (const float*)d_in[10];
    const float* coarse_w= (const float*)d_in[11];
    const float* coarse_b= (const float*)d_in[12];
    const float* detail_w= (const float*)d_in[13];
    const float* detail_b= (const float*)d_in[14];
    const float* merge_w = (const float*)d_in[15];
    const float* merge_b = (const float*)d_in[16];
    float* out = (float*)d_out;

    // ---- workspace layout (float units); ~166 MB ----
    float* wsp  = (float*)d_ws;
    unsigned short* f1hi = (unsigned short*)wsp;         // 9,535,744 bf16 (386*386*64)
    unsigned short* f1lo = f1hi + 9535744;               // 9,535,744 bf16
    float* parts = wsp + 9535744;                        // 1,179,648 f32 (slot 9.4M)
    float* bnp  = parts + 9437184;                       // 256
    float* scores = bnp + 256;                           // 9,216
    int*   topk = (int*)(scores + 9216);                 // 1,024
    unsigned short* B2hi = (unsigned short*)(topk + 1024);   // 36,864 bf16
    unsigned short* B2lo = B2hi + 36864;                     // 36,864 bf16
    unsigned short* Wc16 = B2lo + 36864;                     // 12,582,912 bf16
    unsigned short* Wd16 = Wc16 + 12582912;                  // 3,145,728 bf16
    unsigned short* Wm16 = Wd16 + 3145728;                   // 2,359,296 bf16
    unsigned short* Ac16 = Wm16 + 2359296;                   // 9,437,184 bf16
    unsigned short* dp16 = Ac16 + 9437184;                   // 3,145,728 bf16
    float* part = (float*)(dp16 + 3145728);                  // coarse partials (z=8)
    float* partD = part + 3538944;                           // detail partials (z=8)

    if (ws_size < (size_t)171000000) return;   // graceful fail if ws too small

    const int DETAIL_OFF = 16*576*768;            // 7077888
    const int IDX_OFF    = DETAIL_OFF + 16*64*768;// 7864320

    prep_k<<<194,256,0,stream>>>(bn1_g,bn1_b,bn1_m,bn1_v, bn2_g,bn2_b,bn2_m,bn2_v,
                                 conv2_w, bnp, B2hi, B2lo, f1hi, f1lo);
    cvt3_k<<<70656,256,0,stream>>>(coarse_w, detail_w, merge_w, Wc16, Wd16, Wm16);

    for (int b = 0; b < 16; b++){
        conv1_k<<<2304,512,0,stream>>>(x + (size_t)b*442368, conv1_w, bnp, f1hi, f1lo);
        conv2_mfma_k<<<1024,192,0,stream>>>(f1hi, f1lo, B2hi, B2lo, bnp+128, bnp+192,
                                            Ac16, parts);
        score_k<<<576,64,0,stream>>>(parts, scores + b*576);
        topk_k<<<1,576,0,stream>>>(scores + b*576, topk + b*64, out + IDX_OFF + b*64);
        // coarse (z=8 KL=2048) + detail (z=8 KL=512) in one launch
        gemmcd_k<<<dim3(6,13,8),256,0,stream>>>(Ac16, Wc16, Wd16, topk + b*64,
                                                part, partD);
        // merged reduction: coarse f32 -> out, detail bf16 -> dp16
        reduceboth_k<<<2496,256,0,stream>>>(part, partD, coarse_b, detail_b,
                                            out + (size_t)b*442368,
                                            dp16 + (size_t)b*196608);
    }

    // merge over all batches: M=1024, K=3072
    gemmm_k<<<dim3(6,16,4),256,0,stream>>>(dp16, Wm16, part);
    reduce_k<<<3072,256,0,stream>>>(part, merge_b, out + DETAIL_OFF, 1024, 4);
}

// Round 21
// 2247.486 us; speedup vs baseline: 1.2190x; 1.2190x over previous
//
#include <hip/hip_runtime.h>
#include <math.h>

// Shapes (fixed): B=16, Cin=3, C=64, H=W=384, E=768, P=16, G=24, K_sel=64
// conv2 v5.2 (best, 56us): 144 px/block -> 1024 blocks = exactly 2.0 dispatch rounds
//   at 2 blocks/CU; LDS padded to 54KB. global_load_lds(16) + both-sides XOR swizzle.
// conv1 v5: wave-uniform channel groups (lane=px, wave=cg) -> weight/BN reads become
//   SCALAR loads (s_load via K$), killing the 216 ds_read/thread LDS-pipe bottleneck.
//   Per-thread math identical to r6 -> bit-identical f1.
// gemmcd one-launch coarse+detail (z=8); prep/cvt3/reduceboth merges.
// coarse: M=576,N=768,K=16384  detail(sel): M=256,N=768,K=4096  merge: M=1024,N=768,K=3072

__device__ __forceinline__ float gelu_f(float v){
    return 0.5f*v*(1.0f + erff(v*0.70710678118654752440f));
}
__device__ __forceinline__ unsigned short f2bf(float v){
    unsigned u = __float_as_uint(v);
    return (unsigned short)((u + 0x7FFFu + ((u>>16)&1u)) >> 16);   // RNE
}
__device__ __forceinline__ float bf2f(unsigned short h){
    return __uint_as_float(((unsigned)h)<<16);
}
__device__ __forceinline__ void split2(float v, unsigned short& hi, unsigned short& lo){
    hi = f2bf(v);
    lo = f2bf(v - bf2f(hi));
}

typedef short bf16x8 __attribute__((ext_vector_type(8)));
typedef float f32x4  __attribute__((ext_vector_type(4)));

// ---- merged prep: bid 0 = BN scale/shift, bid 1..144 = conv2 weight split-2,
// bid 145..193 = f1 border zero
__global__ __launch_bounds__(256) void prep_k(
        const float* g1,const float* b1,const float* m1,const float* v1,
        const float* g2,const float* b2,const float* m2,const float* v2,
        const float* __restrict__ w2,
        float* outp, unsigned short* __restrict__ bhi, unsigned short* __restrict__ blo,
        unsigned short* __restrict__ f1hi, unsigned short* __restrict__ f1lo){
    int bid = blockIdx.x;
    if (bid == 0){
        int t = threadIdx.x;
        if (t < 64){
            float s = g1[t]/sqrtf(v1[t]+1e-5f);
            outp[t] = s; outp[64+t] = b1[t]-m1[t]*s;
            float s2 = g2[t]/sqrtf(v2[t]+1e-5f);
            outp[128+t] = s2; outp[192+t] = b2[t]-m2[t]*s2;
        }
    } else if (bid <= 144){
        int idx = (bid-1)*256 + threadIdx.x;
        if (idx < 36864){
            int n = idx/576, kp = idx - n*576;
            int t = kp>>6, ci = kp&63; int kh = t/3, kw = t - kh*3;
            float v = w2[((n*64+ci)*3+kh)*3+kw];
            unsigned short hi,lo; split2(v,hi,lo);
            bhi[n*576+kp]=hi; blo[n*576+kp]=lo;
        }
    } else {
        int idx = (bid-145)*256 + threadIdx.x;
        if (idx < 1540*8){
            int pi = idx>>3, c8 = (idx&7)*8;
            int p;
            if (pi < 386)       p = pi;
            else if (pi < 772)  p = 385*386 + (pi-386);
            else if (pi < 1156) p = (pi-772+1)*386;
            else                p = (pi-1156+1)*386 + 385;
            float4 z = {0.f,0.f,0.f,0.f};
            *(float4*)(f1hi + (size_t)p*64 + c8) = z;
            *(float4*)(f1lo + (size_t)p*64 + c8) = z;
        }
    }
}

// ---- all 3 weight tensors f32 -> bf16 in one launch
__global__ __launch_bounds__(256) void cvt3_k(const float* __restrict__ cw,
                                              const float* __restrict__ dw,
                                              const float* __restrict__ mw,
                                              unsigned short* __restrict__ wc,
                                              unsigned short* __restrict__ wd,
                                              unsigned short* __restrict__ wm){
    int i = blockIdx.x*256 + threadIdx.x;
    if (i < 12582912){
        wc[i] = f2bf(cw[i]);
    } else if (i < 15728640){
        int j = i - 12582912; wd[j] = f2bf(dw[j]);
    } else if (i < 18087936){
        int j = i - 15728640; wm[j] = f2bf(mw[j]);
    }
}

// ---- conv1 v5: 3->64 3x3 SAME + BN + GELU; padded (386x386) NHWC split-2 bf16.
// 64 px/block, 512 thr, 8 waves; lane = pixel, wave = channel-group (cg).
// Weight/BN indices wave-uniform -> scalar loads; LDS holds only the 2.4KB x-halo.
// Per-thread math (j order, operands) identical to r6 -> bit-identical f1.
__global__ __launch_bounds__(512) void conv1_k(const float* __restrict__ x,
                                               const float* __restrict__ w,
                                               const float* __restrict__ bnp,
                                               unsigned short* __restrict__ f1hi,
                                               unsigned short* __restrict__ f1lo){
    __shared__ float xr[9*66];
    int tid = threadIdx.x;
    int bid = blockIdx.x;
    int swb = (bid&7)*288 + (bid>>3);      // 2304 blocks, XCD-aligned with conv2
    int p0 = swb*64;
    int h0 = p0/384, x0 = p0 - h0*384;     // 64 | 384 -> row-uniform block
    for (int t=tid; t<594; t+=512){
        int ci = t/198, rem = t - ci*198;
        int kh = rem/66, col = rem - kh*66;
        int y = h0+kh-1, xx = x0+col-1;
        float v = 0.f;
        if ((unsigned)y<384u && (unsigned)xx<384u)
            v = x[ci*147456 + y*384 + xx];
        xr[(ci*3+kh)*66 + col] = v;
    }
    __syncthreads();
    const int px = tid & 63;                                   // lane
    const int cg = __builtin_amdgcn_readfirstlane(tid >> 6);   // wave-uniform
    const float* wb = w + cg*216;          // (cg*8)*27
    float a[8];
    #pragma unroll
    for (int u=0;u<8;u++) a[u]=0.f;
    #pragma unroll
    for (int ci=0;ci<3;ci++)
        #pragma unroll
        for (int kh=0;kh<3;kh++)
            #pragma unroll
            for (int kw=0;kw<3;kw++){
                const int j = (ci*3+kh)*3+kw;            // same j order as before
                float xv = xr[(ci*3+kh)*66 + px + kw];
                #pragma unroll
                for (int u=0;u<8;u++) a[u] += xv*wb[u*27 + j];   // scalar operand
            }
    unsigned short hs[8], ls[8];
    #pragma unroll
    for (int u=0;u<8;u++){
        int co = cg*8+u;
        float v = gelu_f(a[u]*bnp[co] + bnp[64+co]);     // scalar BN
        split2(v, hs[u], ls[u]);
    }
    size_t off = ((size_t)(h0+1)*386 + (x0+px+1))*64 + cg*8;
    *(float4*)(f1hi + off) = *(float4*)hs;
    *(float4*)(f1lo + off) = *(float4*)ls;
}

// ---- conv2 v5.2: 144 px/block, 1024 blocks = 2.0 rounds at 2 blocks/CU.
// LDS-staged via global_load_lds, 2 barriers/tap, both-sides XOR swizzle.
// LDS padded (BlL +1024 shorts) to 54KB so exactly 2 blocks/CU. One image.
// Fused epilogue: Ac16 bf16 + per-(cell,row,ch) {sum,sumsq} partials.
__global__ __launch_bounds__(192) void conv2_mfma_k(
        const unsigned short* __restrict__ f1hi, const unsigned short* __restrict__ f1lo,
        const unsigned short* __restrict__ bhi,  const unsigned short* __restrict__ blo,
        const float* __restrict__ bnsc, const float* __restrict__ bnsh,
        unsigned short* __restrict__ Ac, float* __restrict__ parts){
    __shared__ __align__(16) unsigned short AhL[144*64], AlL[144*64];
    __shared__ __align__(16) unsigned short BhL[64*64],  BlL[64*64 + 1024]; // pad pins 2/CU
    const int tid = threadIdx.x;
    const int bid = blockIdx.x;
    const int swz = (bid&7)*128 + (bid>>3);    // 1024 blocks, XCD-aligned
    const int bm = swz*144;                    // 144 | 16-aligned; may cross row
    const int wv = tid>>6, lane = tid&63, lm = lane&15, q = lane>>4;

    // staging sources (per-thread constants; tap adds an offset). Per-granule (y,x).
    int aSrc[6];
    #pragma unroll
    for (int i=0;i<6;i++){
        int g = tid + i*192;                   // 0..1151 granules
        int pr = g>>3, p8 = g&7;
        int p = bm + pr;
        int y = p/384, x = p - y*384;
        aSrc[i] = (y*386 + x)*64 + ((p8 ^ (pr&7))<<3);   // pad absorbs -1
    }
    int bSrc[3];
    #pragma unroll
    for (int i=0;i<3;i++){
        int ch = tid + i*192;
        int n = ch>>3, p8 = ch&7;
        bSrc[i] = n*576 + ((p8 ^ (n&7))<<3);
    }
    // ds_read byte addrs (swizzled), per-thread constants
    int aRd[3][2], bRd[4][2];
    #pragma unroll
    for (int mi=0;mi<3;mi++){
        int r = wv*48 + mi*16 + lm;            // 0..143
        #pragma unroll
        for (int h=0;h<2;h++)
            aRd[mi][h] = r*128 + (((h*4+q) ^ (r&7))<<4);
    }
    #pragma unroll
    for (int nj=0;nj<4;nj++){
        int r = nj*16 + lm;
        #pragma unroll
        for (int h=0;h<2;h++)
            bRd[nj][h] = r*128 + (((h*4+q) ^ (r&7))<<4);
    }

    f32x4 acc[3][4];
    #pragma unroll
    for (int i=0;i<3;i++)
        #pragma unroll
        for (int j=0;j<4;j++) acc[i][j] = (f32x4){0.f,0.f,0.f,0.f};

    for (int t9=0; t9<9; t9++){
        const int kh = t9/3, kw = t9 - kh*3;
        const int aoff = (kh*386 + kw)*64;
        const int boff = t9*64;
        #pragma unroll
        for (int i=0;i<6;i++){
            __builtin_amdgcn_global_load_lds(f1hi + aSrc[i] + aoff, &AhL[(tid+i*192)*8], 16, 0, 0);
            __builtin_amdgcn_global_load_lds(f1lo + aSrc[i] + aoff, &AlL[(tid+i*192)*8], 16, 0, 0);
        }
        #pragma unroll
        for (int i=0;i<3;i++){
            int ch = tid + i*192;
            if (ch < 512){   // wave-uniform: i=2 skips wave 2 entirely
                __builtin_amdgcn_global_load_lds(bhi + bSrc[i] + boff, &BhL[ch*8], 16, 0, 0);
                __builtin_amdgcn_global_load_lds(blo + bSrc[i] + boff, &BlL[ch*8], 16, 0, 0);
            }
        }
        __syncthreads();
        #pragma unroll
        for (int h=0; h<2; h++){
            bf16x8 ah[3], al[3], bh8[4], bl8[4];
            #pragma unroll
            for (int mi=0;mi<3;mi++){
                ah[mi] = *(const bf16x8*)((const char*)AhL + aRd[mi][h]);
                al[mi] = *(const bf16x8*)((const char*)AlL + aRd[mi][h]);
            }
            #pragma unroll
            for (int nj=0;nj<4;nj++){
                bh8[nj] = *(const bf16x8*)((const char*)BhL + bRd[nj][h]);
                bl8[nj] = *(const bf16x8*)((const char*)BlL + bRd[nj][h]);
            }
            #pragma unroll
            for (int mi=0;mi<3;mi++)
                #pragma unroll
                for (int nj=0;nj<4;nj++){
                    acc[mi][nj] = __builtin_amdgcn_mfma_f32_16x16x32_bf16(ah[mi], bh8[nj], acc[mi][nj], 0,0,0);
                    acc[mi][nj] = __builtin_amdgcn_mfma_f32_16x16x32_bf16(al[mi], bh8[nj], acc[mi][nj], 0,0,0);
                    acc[mi][nj] = __builtin_amdgcn_mfma_f32_16x16x32_bf16(ah[mi], bl8[nj], acc[mi][nj], 0,0,0);
                }
        }
        __syncthreads();
    }

    // ---- fused epilogue: gelu -> Ac16 bf16 + per-cell-row {sum,sumsq} partials
    // 16-px groups are 16-aligned and never cross a row (16 | 384); per-mi (y,x).
    #pragma unroll
    for (int mi=0;mi<3;mi++){
        const int p0m = bm + wv*48 + mi*16;
        const int ym = p0m/384, xm = p0m - ym*384;
        const int cell = (ym>>4)*24 + (xm>>4);
        const int py = ym&15;
        unsigned short* acb = Ac + (size_t)cell*16384;
        float* pp = parts + (size_t)(cell*16 + py)*128;   // 64 ch * 2 floats
        #pragma unroll
        for (int nj=0;nj<4;nj++){
            const int n = nj*16 + lm;
            const float sc = bnsc[n], sh = bnsh[n];
            float g0 = gelu_f(acc[mi][nj][0]*sc + sh);
            float g1 = gelu_f(acc[mi][nj][1]*sc + sh);
            float g2 = gelu_f(acc[mi][nj][2]*sc + sh);
            float g3 = gelu_f(acc[mi][nj][3]*sc + sh);
            // Ac16: k = n*256 + py*16 + (q*4 + r), 8B store
            unsigned int u0 = (unsigned)f2bf(g0) | ((unsigned)f2bf(g1)<<16);
            unsigned int u1 = (unsigned)f2bf(g2) | ((unsigned)f2bf(g3)<<16);
            uint2 uu; uu.x = u0; uu.y = u1;
            *(uint2*)(acb + (size_t)n*256 + py*16 + q*4) = uu;
            // partial sum/sumsq over this 16-px cell-row slice
            float s  = ((g0+g1)+g2)+g3;
            float ss = ((g0*g0+g1*g1)+g2*g2)+g3*g3;
            s  += __shfl_xor(s,16);  s  += __shfl_xor(s,32);
            ss += __shfl_xor(ss,16); ss += __shfl_xor(ss,32);
            if (q==0){
                float2 v; v.x = s; v.y = ss;
                *(float2*)(pp + n*2) = v;
            }
        }
    }
}

// ---- per-cell score from partials: var = E[x^2]-E[x]^2 per ch, mean over ch
__global__ __launch_bounds__(64) void score_k(const float* __restrict__ parts,
                                              float* __restrict__ scores){
    const int cell = blockIdx.x;       // 0..575
    const int n = threadIdx.x;         // channel
    float s = 0.f, ss = 0.f;
    #pragma unroll
    for (int py=0;py<16;py++){
        float2 v = *(const float2*)(parts + (size_t)(cell*16+py)*128 + n*2);
        s += v.x; ss += v.y;
    }
    float mean = s*(1.f/256.f);
    float var  = ss*(1.f/256.f) - mean*mean;
    var += __shfl_down(var,32); var += __shfl_down(var,16);
    var += __shfl_down(var,8);  var += __shfl_down(var,4);
    var += __shfl_down(var,2);  var += __shfl_down(var,1);
    if (n==0) scores[cell] = var*(1.f/64.f);
}

// ---- gemm body (r6-exact math): tile M=64 x N=128, 256 thr (4 waves), K-split z.
// Staging via global_load_lds(16); linear 128B LDS rows; both-sides XOR swizzle.
// LDS tile is passed in (single allocation in the calling kernel).
template<int MODE, int KL, int MT>
__device__ __forceinline__ void gemm_body(const unsigned short* __restrict__ A,
                                          const unsigned short* __restrict__ W,
                                          const int* __restrict__ topk,
                                          float* __restrict__ part,
                                          unsigned short* As, unsigned short* Bs,
                                          int nt, int mt, int z){
    constexpr int KT = (MODE==0)?16384:(MODE==1)?4096:3072;   // W row length
    const int tid = threadIdx.x;
    const int m0 = mt*64, n0 = nt*128;
    const int wv = tid>>6, lane = tid&63;
    const int lm = lane&15, q = lane>>4;

    const int srow = tid>>3, sslot = tid&7;
    const int sx = (sslot ^ (srow&7))*8;          // logical k offset (shorts)
    size_t aSb[2];
    #pragma unroll
    for (int it=0;it<2;it++){
        int row = srow + it*32;                   // (row&7) == (srow&7)
        if (MODE==1){
            int t = m0 + row; int sel = t>>2, dd = t&3;
            int cell = topk[sel];
            aSb[it] = (size_t)cell*16384 + (dd>>1)*128 + (dd&1)*8 + sx*2;
        } else {
            aSb[it] = (size_t)(m0+row)*KT + sx;
        }
    }
    size_t bSb[4];
    #pragma unroll
    for (int it=0;it<4;it++)
        bSb[it] = (size_t)(n0 + srow + it*32)*KT + sx;

    int aRd[4][2], bRd[2][2];
    #pragma unroll
    for (int mi=0;mi<4;mi++){
        int r = mi*16 + lm;
        #pragma unroll
        for (int h=0;h<2;h++)
            aRd[mi][h] = r*128 + (((h*4+q) ^ (r&7))<<4);
    }
    #pragma unroll
    for (int nj=0;nj<2;nj++){
        int r = wv*32 + nj*16 + lm;
        #pragma unroll
        for (int h=0;h<2;h++)
            bRd[nj][h] = r*128 + (((h*4+q) ^ (r&7))<<4);
    }

    f32x4 acc[4][2];
    #pragma unroll
    for (int i=0;i<4;i++)
        #pragma unroll
        for (int j=0;j<2;j++)
            acc[i][j] = (f32x4){0.f,0.f,0.f,0.f};

    const int kb0 = z*KL;
    for (int kb = kb0; kb < kb0+KL; kb += 64){
        #pragma unroll
        for (int it=0;it<2;it++){
            const unsigned short* src = (MODE==1) ? (A + aSb[it] + (size_t)(kb>>6)*256)
                                                  : (A + aSb[it] + kb);
            __builtin_amdgcn_global_load_lds(src, &As[(tid + it*256)*8], 16, 0, 0);
        }
        #pragma unroll
        for (int it=0;it<4;it++)
            __builtin_amdgcn_global_load_lds(W + bSb[it] + kb, &Bs[(tid + it*256)*8], 16, 0, 0);
        __syncthreads();
        #pragma unroll
        for (int h=0;h<2;h++){
            bf16x8 af[4], bb[2];
            #pragma unroll
            for (int mi=0;mi<4;mi++) af[mi] = *(const bf16x8*)((const char*)As + aRd[mi][h]);
            #pragma unroll
            for (int nj=0;nj<2;nj++) bb[nj] = *(const bf16x8*)((const char*)Bs + bRd[nj][h]);
            #pragma unroll
            for (int mi=0;mi<4;mi++)
                #pragma unroll
                for (int nj=0;nj<2;nj++)
                    acc[mi][nj] = __builtin_amdgcn_mfma_f32_16x16x32_bf16(af[mi], bb[nj], acc[mi][nj], 0,0,0);
        }
        __syncthreads();
    }

    float* pz = part + (size_t)z*MT*768;
    #pragma unroll
    for (int mi=0;mi<4;mi++)
        #pragma unroll
        for (int nj=0;nj<2;nj++)
            #pragma unroll
            for (int r=0;r<4;r++){
                int m = m0 + mi*16 + q*4 + r;
                int n = n0 + wv*32 + nj*16 + lm;
                pz[m*768 + n] = acc[mi][nj][r];
            }
}

// ---- coarse + detail GEMM in one launch: grid (6, 13, 8); y<9 coarse, else detail
__global__ __launch_bounds__(256) void gemmcd_k(const unsigned short* __restrict__ Ac,
                                                const unsigned short* __restrict__ Wc,
                                                const unsigned short* __restrict__ Wd,
                                                const int* __restrict__ topk,
                                                float* __restrict__ partC,
                                                float* __restrict__ partD){
    __shared__ __align__(16) unsigned short As[64*64];
    __shared__ __align__(16) unsigned short Bs[128*64];
    const int mt = blockIdx.y;
    if (mt < 9)
        gemm_body<0,2048,576>(Ac, Wc, nullptr, partC, As, Bs, blockIdx.x, mt, blockIdx.z);
    else
        gemm_body<1,512,256>(Ac, Wd, topk, partD, As, Bs, blockIdx.x, mt-9, blockIdx.z);
}

// ---- merge GEMM (unchanged structure)
__global__ __launch_bounds__(256) void gemmm_k(const unsigned short* __restrict__ A,
                                               const unsigned short* __restrict__ W,
                                               float* __restrict__ part){
    __shared__ __align__(16) unsigned short As[64*64];
    __shared__ __align__(16) unsigned short Bs[128*64];
    gemm_body<2,768,1024>(A, W, nullptr, part, As, Bs, blockIdx.x, blockIdx.y, blockIdx.z);
}

// ---- merged per-batch reduction: coarse (f32 out) + detail (bf16 out), both z=8
__global__ __launch_bounds__(256) void reduceboth_k(const float* __restrict__ partC,
                                                    const float* __restrict__ partD,
                                                    const float* __restrict__ cb,
                                                    const float* __restrict__ db,
                                                    float* __restrict__ outC,
                                                    unsigned short* __restrict__ outD){
    int bid = blockIdx.x;
    if (bid < 1728){
        int idx = bid*256 + threadIdx.x;          // 0..442367
        int col = idx % 768;
        float s = cb[col];
        #pragma unroll
        for (int i=0;i<8;i++) s += partC[(size_t)i*442368 + idx];
        outC[idx] = s;
    } else {
        int idx = (bid-1728)*256 + threadIdx.x;   // 0..196607
        int col = idx % 768;
        float s = db[col];
        #pragma unroll
        for (int i=0;i<8;i++) s += partD[(size_t)i*196608 + idx];
        outD[idx] = f2bf(s);
    }
}

// ---- final merge reduction: sum K-split partials + bias -> f32
__global__ __launch_bounds__(256) void reduce_k(const float* __restrict__ partials,
                                                const float* __restrict__ bias,
                                                float* __restrict__ outp,
                                                int MTOT, int NSPLIT){
    int idx = blockIdx.x*256 + threadIdx.x;
    int col = idx % 768;
    float s = bias[col];
    for (int i=0;i<NSPLIT;i++) s += partials[(size_t)i*MTOT*768 + idx];
    outp[idx] = s;
}

// ---- top-64 of 576 via rank counting; jax tie-break (lower idx first), one shot
__global__ __launch_bounds__(576) void topk_k(const float* __restrict__ scores,
                                              int* __restrict__ topk,
                                              float* __restrict__ outf){
    __shared__ float s[576];
    int t = threadIdx.x;
    s[t] = scores[t];
    __syncthreads();
    float v = s[t];
    int cnt = 0;
    for (int j=0;j<576;j++){
        float u = s[j];
        cnt += (u > v) || (u == v && j < t);
    }
    if (cnt < 64){ topk[cnt] = t; outf[cnt] = (float)t; }
}

extern "C" void kernel_launch(void* const* d_in, const int* in_sizes, int n_in,
                              void* d_out, int out_size, void* d_ws, size_t ws_size,
                              hipStream_t stream){
    const float* x       = (const float*)d_in[0];
    const float* conv1_w = (const float*)d_in[1];
    const float* bn1_g   = (const float*)d_in[2];
    const float* bn1_b   = (const float*)d_in[3];
    const float* bn1_m   = (const float*)d_in[4];
    const float* bn1_v   = (const float*)d_in[5];
    const float* conv2_w = (const float*)d_in[6];
    const float* bn2_g   = (const float*)d_in[7];
    const float* bn2_b   = (const float*)d_in[8];
    const float* bn2_m   = (const float*)d_in[9];
    const float* bn2_v   = (const float*)d_in[10];
    const float* coarse_w= (const float*)d_in[11];
    const float* coarse_b= (const float*)d_in[12];
    const float* detail_w= (const float*)d_in[13];
    const float* detail_b= (const float*)d_in[14];
    const float* merge_w = (const float*)d_in[15];
    const float* merge_b = (const float*)d_in[16];
    float* out = (float*)d_out;

    // ---- workspace layout (float units); ~166 MB ----
    float* wsp  = (float*)d_ws;
    unsigned short* f1hi = (unsigned short*)wsp;         // 9,535,744 bf16 (386*386*64)
    unsigned short* f1lo = f1hi + 9535744;               // 9,535,744 bf16
    float* parts = wsp + 9535744;                        // 1,179,648 f32 (slot 9.4M)
    float* bnp  = parts + 9437184;                       // 256
    float* scores = bnp + 256;                           // 9,216
    int*   topk = (int*)(scores + 9216);                 // 1,024
    unsigned short* B2hi = (unsigned short*)(topk + 1024);   // 36,864 bf16
    unsigned short* B2lo = B2hi + 36864;                     // 36,864 bf16
    unsigned short* Wc16 = B2lo + 36864;                     // 12,582,912 bf16
    unsigned short* Wd16 = Wc16 + 12582912;                  // 3,145,728 bf16
    unsigned short* Wm16 = Wd16 + 3145728;                   // 2,359,296 bf16
    unsigned short* Ac16 = Wm16 + 2359296;                   // 9,437,184 bf16
    unsigned short* dp16 = Ac16 + 9437184;                   // 3,145,728 bf16
    float* part = (float*)(dp16 + 3145728);                  // coarse partials (z=8)
    float* partD = part + 3538944;                           // detail partials (z=8)

    if (ws_size < (size_t)171000000) return;   // graceful fail if ws too small

    const int DETAIL_OFF = 16*576*768;            // 7077888
    const int IDX_OFF    = DETAIL_OFF + 16*64*768;// 7864320

    prep_k<<<194,256,0,stream>>>(bn1_g,bn1_b,bn1_m,bn1_v, bn2_g,bn2_b,bn2_m,bn2_v,
                                 conv2_w, bnp, B2hi, B2lo, f1hi, f1lo);
    cvt3_k<<<70656,256,0,stream>>>(coarse_w, detail_w, merge_w, Wc16, Wd16, Wm16);

    for (int b = 0; b < 16; b++){
        conv1_k<<<2304,512,0,stream>>>(x + (size_t)b*442368, conv1_w, bnp, f1hi, f1lo);
        conv2_mfma_k<<<1024,192,0,stream>>>(f1hi, f1lo, B2hi, B2lo, bnp+128, bnp+192,
                                            Ac16, parts);
        score_k<<<576,64,0,stream>>>(parts, scores + b*576);
        topk_k<<<1,576,0,stream>>>(scores + b*576, topk + b*64, out + IDX_OFF + b*64);
        // coarse (z=8 KL=2048) + detail (z=8 KL=512) in one launch
        gemmcd_k<<<dim3(6,13,8),256,0,stream>>>(Ac16, Wc16, Wd16, topk + b*64,
                                                part, partD);
        // merged reduction: coarse f32 -> out, detail bf16 -> dp16
        reduceboth_k<<<2496,256,0,stream>>>(part, partD, coarse_b, detail_b,
                                            out + (size_t)b*442368,
                                            dp16 + (size_t)b*196608);
    }

    // merge over all batches: M=1024, K=3072
    gemmm_k<<<dim3(6,16,4),256,0,stream>>>(dp16, Wm16, part);
    reduce_k<<<3072,256,0,stream>>>(part, merge_b, out + DETAIL_OFF, 1024, 4);
}

// Round 24
// 2030.043 us; speedup vs baseline: 1.3496x; 1.1071x over previous
//
#include <hip/hip_runtime.h>
#include <math.h>

// Shapes (fixed): B=16, Cin=3, C=64, H=W=384, E=768, P=16, G=24, K_sel=64
// conv2 v5.2 (56us): 144 px/block -> 1024 blocks = exactly 2.0 dispatch rounds
//   at 2 blocks/CU; LDS padded to 54KB. global_load_lds(16) + both-sides XOR swizzle.
// conv1 v5 (~28us): wave-uniform channel groups -> scalar weight/BN reads.
// gemmcd v2: + bijective chunked XCD swizzle (624=8x78) so same-W-panel blocks
//   colocate per XCD (T1). Same block set -> bit-identical.
// coarse: M=576,N=768,K=16384  detail(sel): M=256,N=768,K=4096  merge: M=1024,N=768,K=3072
// [3rd submission of round-22 kernel — two prior benches died of container infra failure
//  at connection setup (pre-compile); kernel content uninvolved]

__device__ __forceinline__ float gelu_f(float v){
    return 0.5f*v*(1.0f + erff(v*0.70710678118654752440f));
}
__device__ __forceinline__ unsigned short f2bf(float v){
    unsigned u = __float_as_uint(v);
    return (unsigned short)((u + 0x7FFFu + ((u>>16)&1u)) >> 16);   // RNE
}
__device__ __forceinline__ float bf2f(unsigned short h){
    return __uint_as_float(((unsigned)h)<<16);
}
__device__ __forceinline__ void split2(float v, unsigned short& hi, unsigned short& lo){
    hi = f2bf(v);
    lo = f2bf(v - bf2f(hi));
}

typedef short bf16x8 __attribute__((ext_vector_type(8)));
typedef float f32x4  __attribute__((ext_vector_type(4)));

// ---- merged prep: bid 0 = BN scale/shift, bid 1..144 = conv2 weight split-2,
// bid 145..193 = f1 border zero
__global__ __launch_bounds__(256) void prep_k(
        const float* g1,const float* b1,const float* m1,const float* v1,
        const float* g2,const float* b2,const float* m2,const float* v2,
        const float* __restrict__ w2,
        float* outp, unsigned short* __restrict__ bhi, unsigned short* __restrict__ blo,
        unsigned short* __restrict__ f1hi, unsigned short* __restrict__ f1lo){
    int bid = blockIdx.x;
    if (bid == 0){
        int t = threadIdx.x;
        if (t < 64){
            float s = g1[t]/sqrtf(v1[t]+1e-5f);
            outp[t] = s; outp[64+t] = b1[t]-m1[t]*s;
            float s2 = g2[t]/sqrtf(v2[t]+1e-5f);
            outp[128+t] = s2; outp[192+t] = b2[t]-m2[t]*s2;
        }
    } else if (bid <= 144){
        int idx = (bid-1)*256 + threadIdx.x;
        if (idx < 36864){
            int n = idx/576, kp = idx - n*576;
            int t = kp>>6, ci = kp&63; int kh = t/3, kw = t - kh*3;
            float v = w2[((n*64+ci)*3+kh)*3+kw];
            unsigned short hi,lo; split2(v,hi,lo);
            bhi[n*576+kp]=hi; blo[n*576+kp]=lo;
        }
    } else {
        int idx = (bid-145)*256 + threadIdx.x;
        if (idx < 1540*8){
            int pi = idx>>3, c8 = (idx&7)*8;
            int p;
            if (pi < 386)       p = pi;
            else if (pi < 772)  p = 385*386 + (pi-386);
            else if (pi < 1156) p = (pi-772+1)*386;
            else                p = (pi-1156+1)*386 + 385;
            float4 z = {0.f,0.f,0.f,0.f};
            *(float4*)(f1hi + (size_t)p*64 + c8) = z;
            *(float4*)(f1lo + (size_t)p*64 + c8) = z;
        }
    }
}

// ---- all 3 weight tensors f32 -> bf16 in one launch
__global__ __launch_bounds__(256) void cvt3_k(const float* __restrict__ cw,
                                              const float* __restrict__ dw,
                                              const float* __restrict__ mw,
                                              unsigned short* __restrict__ wc,
                                              unsigned short* __restrict__ wd,
                                              unsigned short* __restrict__ wm){
    int i = blockIdx.x*256 + threadIdx.x;
    if (i < 12582912){
        wc[i] = f2bf(cw[i]);
    } else if (i < 15728640){
        int j = i - 12582912; wd[j] = f2bf(dw[j]);
    } else if (i < 18087936){
        int j = i - 15728640; wm[j] = f2bf(mw[j]);
    }
}

// ---- conv1 v5: 3->64 3x3 SAME + BN + GELU; padded (386x386) NHWC split-2 bf16.
// 64 px/block, 512 thr, 8 waves; lane = pixel, wave = channel-group (cg).
// Weight/BN indices wave-uniform -> scalar loads; LDS holds only the 2.4KB x-halo.
__global__ __launch_bounds__(512) void conv1_k(const float* __restrict__ x,
                                               const float* __restrict__ w,
                                               const float* __restrict__ bnp,
                                               unsigned short* __restrict__ f1hi,
                                               unsigned short* __restrict__ f1lo){
    __shared__ float xr[9*66];
    int tid = threadIdx.x;
    int bid = blockIdx.x;
    int swb = (bid&7)*288 + (bid>>3);      // 2304 blocks, XCD-aligned with conv2
    int p0 = swb*64;
    int h0 = p0/384, x0 = p0 - h0*384;     // 64 | 384 -> row-uniform block
    for (int t=tid; t<594; t+=512){
        int ci = t/198, rem = t - ci*198;
        int kh = rem/66, col = rem - kh*66;
        int y = h0+kh-1, xx = x0+col-1;
        float v = 0.f;
        if ((unsigned)y<384u && (unsigned)xx<384u)
            v = x[ci*147456 + y*384 + xx];
        xr[(ci*3+kh)*66 + col] = v;
    }
    __syncthreads();
    const int px = tid & 63;                                   // lane
    const int cg = __builtin_amdgcn_readfirstlane(tid >> 6);   // wave-uniform
    const float* wb = w + cg*216;          // (cg*8)*27
    float a[8];
    #pragma unroll
    for (int u=0;u<8;u++) a[u]=0.f;
    #pragma unroll
    for (int ci=0;ci<3;ci++)
        #pragma unroll
        for (int kh=0;kh<3;kh++)
            #pragma unroll
            for (int kw=0;kw<3;kw++){
                const int j = (ci*3+kh)*3+kw;            // same j order as before
                float xv = xr[(ci*3+kh)*66 + px + kw];
                #pragma unroll
                for (int u=0;u<8;u++) a[u] += xv*wb[u*27 + j];   // scalar operand
            }
    unsigned short hs[8], ls[8];
    #pragma unroll
    for (int u=0;u<8;u++){
        int co = cg*8+u;
        float v = gelu_f(a[u]*bnp[co] + bnp[64+co]);     // scalar BN
        split2(v, hs[u], ls[u]);
    }
    size_t off = ((size_t)(h0+1)*386 + (x0+px+1))*64 + cg*8;
    *(float4*)(f1hi + off) = *(float4*)hs;
    *(float4*)(f1lo + off) = *(float4*)ls;
}

// ---- conv2 v5.2: 144 px/block, 1024 blocks = 2.0 rounds at 2 blocks/CU.
// LDS-staged via global_load_lds, 2 barriers/tap, both-sides XOR swizzle.
// LDS padded (BlL +1024 shorts) to 54KB so exactly 2 blocks/CU. One image.
// Fused epilogue: Ac16 bf16 + per-(cell,row,ch) {sum,sumsq} partials.
__global__ __launch_bounds__(192) void conv2_mfma_k(
        const unsigned short* __restrict__ f1hi, const unsigned short* __restrict__ f1lo,
        const unsigned short* __restrict__ bhi,  const unsigned short* __restrict__ blo,
        const float* __restrict__ bnsc, const float* __restrict__ bnsh,
        unsigned short* __restrict__ Ac, float* __restrict__ parts){
    __shared__ __align__(16) unsigned short AhL[144*64], AlL[144*64];
    __shared__ __align__(16) unsigned short BhL[64*64],  BlL[64*64 + 1024]; // pad pins 2/CU
    const int tid = threadIdx.x;
    const int bid = blockIdx.x;
    const int swz = (bid&7)*128 + (bid>>3);    // 1024 blocks, XCD-aligned
    const int bm = swz*144;                    // 144 | 16-aligned; may cross row
    const int wv = tid>>6, lane = tid&63, lm = lane&15, q = lane>>4;

    // staging sources (per-thread constants; tap adds an offset). Per-granule (y,x).
    int aSrc[6];
    #pragma unroll
    for (int i=0;i<6;i++){
        int g = tid + i*192;                   // 0..1151 granules
        int pr = g>>3, p8 = g&7;
        int p = bm + pr;
        int y = p/384, x = p - y*384;
        aSrc[i] = (y*386 + x)*64 + ((p8 ^ (pr&7))<<3);   // pad absorbs -1
    }
    int bSrc[3];
    #pragma unroll
    for (int i=0;i<3;i++){
        int ch = tid + i*192;
        int n = ch>>3, p8 = ch&7;
        bSrc[i] = n*576 + ((p8 ^ (n&7))<<3);
    }
    // ds_read byte addrs (swizzled), per-thread constants
    int aRd[3][2], bRd[4][2];
    #pragma unroll
    for (int mi=0;mi<3;mi++){
        int r = wv*48 + mi*16 + lm;            // 0..143
        #pragma unroll
        for (int h=0;h<2;h++)
            aRd[mi][h] = r*128 + (((h*4+q) ^ (r&7))<<4);
    }
    #pragma unroll
    for (int nj=0;nj<4;nj++){
        int r = nj*16 + lm;
        #pragma unroll
        for (int h=0;h<2;h++)
            bRd[nj][h] = r*128 + (((h*4+q) ^ (r&7))<<4);
    }

    f32x4 acc[3][4];
    #pragma unroll
    for (int i=0;i<3;i++)
        #pragma unroll
        for (int j=0;j<4;j++) acc[i][j] = (f32x4){0.f,0.f,0.f,0.f};

    for (int t9=0; t9<9; t9++){
        const int kh = t9/3, kw = t9 - kh*3;
        const int aoff = (kh*386 + kw)*64;
        const int boff = t9*64;
        #pragma unroll
        for (int i=0;i<6;i++){
            __builtin_amdgcn_global_load_lds(f1hi + aSrc[i] + aoff, &AhL[(tid+i*192)*8], 16, 0, 0);
            __builtin_amdgcn_global_load_lds(f1lo + aSrc[i] + aoff, &AlL[(tid+i*192)*8], 16, 0, 0);
        }
        #pragma unroll
        for (int i=0;i<3;i++){
            int ch = tid + i*192;
            if (ch < 512){   // wave-uniform: i=2 skips wave 2 entirely
                __builtin_amdgcn_global_load_lds(bhi + bSrc[i] + boff, &BhL[ch*8], 16, 0, 0);
                __builtin_amdgcn_global_load_lds(blo + bSrc[i] + boff, &BlL[ch*8], 16, 0, 0);
            }
        }
        __syncthreads();
        #pragma unroll
        for (int h=0; h<2; h++){
            bf16x8 ah[3], al[3], bh8[4], bl8[4];
            #pragma unroll
            for (int mi=0;mi<3;mi++){
                ah[mi] = *(const bf16x8*)((const char*)AhL + aRd[mi][h]);
                al[mi] = *(const bf16x8*)((const char*)AlL + aRd[mi][h]);
            }
            #pragma unroll
            for (int nj=0;nj<4;nj++){
                bh8[nj] = *(const bf16x8*)((const char*)BhL + bRd[nj][h]);
                bl8[nj] = *(const bf16x8*)((const char*)BlL + bRd[nj][h]);
            }
            #pragma unroll
            for (int mi=0;mi<3;mi++)
                #pragma unroll
                for (int nj=0;nj<4;nj++){
                    acc[mi][nj] = __builtin_amdgcn_mfma_f32_16x16x32_bf16(ah[mi], bh8[nj], acc[mi][nj], 0,0,0);
                    acc[mi][nj] = __builtin_amdgcn_mfma_f32_16x16x32_bf16(al[mi], bh8[nj], acc[mi][nj], 0,0,0);
                    acc[mi][nj] = __builtin_amdgcn_mfma_f32_16x16x32_bf16(ah[mi], bl8[nj], acc[mi][nj], 0,0,0);
                }
        }
        __syncthreads();
    }

    // ---- fused epilogue: gelu -> Ac16 bf16 + per-cell-row {sum,sumsq} partials
    // 16-px groups are 16-aligned and never cross a row (16 | 384); per-mi (y,x).
    #pragma unroll
    for (int mi=0;mi<3;mi++){
        const int p0m = bm + wv*48 + mi*16;
        const int ym = p0m/384, xm = p0m - ym*384;
        const int cell = (ym>>4)*24 + (xm>>4);
        const int py = ym&15;
        unsigned short* acb = Ac + (size_t)cell*16384;
        float* pp = parts + (size_t)(cell*16 + py)*128;   // 64 ch * 2 floats
        #pragma unroll
        for (int nj=0;nj<4;nj++){
            const int n = nj*16 + lm;
            const float sc = bnsc[n], sh = bnsh[n];
            float g0 = gelu_f(acc[mi][nj][0]*sc + sh);
            float g1 = gelu_f(acc[mi][nj][1]*sc + sh);
            float g2 = gelu_f(acc[mi][nj][2]*sc + sh);
            float g3 = gelu_f(acc[mi][nj][3]*sc + sh);
            // Ac16: k = n*256 + py*16 + (q*4 + r), 8B store
            unsigned int u0 = (unsigned)f2bf(g0) | ((unsigned)f2bf(g1)<<16);
            unsigned int u1 = (unsigned)f2bf(g2) | ((unsigned)f2bf(g3)<<16);
            uint2 uu; uu.x = u0; uu.y = u1;
            *(uint2*)(acb + (size_t)n*256 + py*16 + q*4) = uu;
            // partial sum/sumsq over this 16-px cell-row slice
            float s  = ((g0+g1)+g2)+g3;
            float ss = ((g0*g0+g1*g1)+g2*g2)+g3*g3;
            s  += __shfl_xor(s,16);  s  += __shfl_xor(s,32);
            ss += __shfl_xor(ss,16); ss += __shfl_xor(ss,32);
            if (q==0){
                float2 v; v.x = s; v.y = ss;
                *(float2*)(pp + n*2) = v;
            }
        }
    }
}

// ---- per-cell score from partials: var = E[x^2]-E[x]^2 per ch, mean over ch
__global__ __launch_bounds__(64) void score_k(const float* __restrict__ parts,
                                              float* __restrict__ scores){
    const int cell = blockIdx.x;       // 0..575
    const int n = threadIdx.x;         // channel
    float s = 0.f, ss = 0.f;
    #pragma unroll
    for (int py=0;py<16;py++){
        float2 v = *(const float2*)(parts + (size_t)(cell*16+py)*128 + n*2);
        s += v.x; ss += v.y;
    }
    float mean = s*(1.f/256.f);
    float var  = ss*(1.f/256.f) - mean*mean;
    var += __shfl_down(var,32); var += __shfl_down(var,16);
    var += __shfl_down(var,8);  var += __shfl_down(var,4);
    var += __shfl_down(var,2);  var += __shfl_down(var,1);
    if (n==0) scores[cell] = var*(1.f/64.f);
}

// ---- gemm body (r6-exact math): tile M=64 x N=128, 256 thr (4 waves), K-split z.
// Staging via global_load_lds(16); linear 128B LDS rows; both-sides XOR swizzle.
// LDS tile is passed in (single allocation in the calling kernel).
template<int MODE, int KL, int MT>
__device__ __forceinline__ void gemm_body(const unsigned short* __restrict__ A,
                                          const unsigned short* __restrict__ W,
                                          const int* __restrict__ topk,
                                          float* __restrict__ part,
                                          unsigned short* As, unsigned short* Bs,
                                          int nt, int mt, int z){
    constexpr int KT = (MODE==0)?16384:(MODE==1)?4096:3072;   // W row length
    const int tid = threadIdx.x;
    const int m0 = mt*64, n0 = nt*128;
    const int wv = tid>>6, lane = tid&63;
    const int lm = lane&15, q = lane>>4;

    const int srow = tid>>3, sslot = tid&7;
    const int sx = (sslot ^ (srow&7))*8;          // logical k offset (shorts)
    size_t aSb[2];
    #pragma unroll
    for (int it=0;it<2;it++){
        int row = srow + it*32;                   // (row&7) == (srow&7)
        if (MODE==1){
            int t = m0 + row; int sel = t>>2, dd = t&3;
            int cell = topk[sel];
            aSb[it] = (size_t)cell*16384 + (dd>>1)*128 + (dd&1)*8 + sx*2;
        } else {
            aSb[it] = (size_t)(m0+row)*KT + sx;
        }
    }
    size_t bSb[4];
    #pragma unroll
    for (int it=0;it<4;it++)
        bSb[it] = (size_t)(n0 + srow + it*32)*KT + sx;

    int aRd[4][2], bRd[2][2];
    #pragma unroll
    for (int mi=0;mi<4;mi++){
        int r = mi*16 + lm;
        #pragma unroll
        for (int h=0;h<2;h++)
            aRd[mi][h] = r*128 + (((h*4+q) ^ (r&7))<<4);
    }
    #pragma unroll
    for (int nj=0;nj<2;nj++){
        int r = wv*32 + nj*16 + lm;
        #pragma unroll
        for (int h=0;h<2;h++)
            bRd[nj][h] = r*128 + (((h*4+q) ^ (r&7))<<4);
    }

    f32x4 acc[4][2];
    #pragma unroll
    for (int i=0;i<4;i++)
        #pragma unroll
        for (int j=0;j<2;j++)
            acc[i][j] = (f32x4){0.f,0.f,0.f,0.f};

    const int kb0 = z*KL;
    for (int kb = kb0; kb < kb0+KL; kb += 64){
        #pragma unroll
        for (int it=0;it<2;it++){
            const unsigned short* src = (MODE==1) ? (A + aSb[it] + (size_t)(kb>>6)*256)
                                                  : (A + aSb[it] + kb);
            __builtin_amdgcn_global_load_lds(src, &As[(tid + it*256)*8], 16, 0, 0);
        }
        #pragma unroll
        for (int it=0;it<4;it++)
            __builtin_amdgcn_global_load_lds(W + bSb[it] + kb, &Bs[(tid + it*256)*8], 16, 0, 0);
        __syncthreads();
        #pragma unroll
        for (int h=0;h<2;h++){
            bf16x8 af[4], bb[2];
            #pragma unroll
            for (int mi=0;mi<4;mi++) af[mi] = *(const bf16x8*)((const char*)As + aRd[mi][h]);
            #pragma unroll
            for (int nj=0;nj<2;nj++) bb[nj] = *(const bf16x8*)((const char*)Bs + bRd[nj][h]);
            #pragma unroll
            for (int mi=0;mi<4;mi++)
                #pragma unroll
                for (int nj=0;nj<2;nj++)
                    acc[mi][nj] = __builtin_amdgcn_mfma_f32_16x16x32_bf16(af[mi], bb[nj], acc[mi][nj], 0,0,0);
        }
        __syncthreads();
    }

    float* pz = part + (size_t)z*MT*768;
    #pragma unroll
    for (int mi=0;mi<4;mi++)
        #pragma unroll
        for (int nj=0;nj<2;nj++)
            #pragma unroll
            for (int r=0;r<4;r++){
                int m = m0 + mi*16 + q*4 + r;
                int n = n0 + wv*32 + nj*16 + lm;
                pz[m*768 + n] = acc[mi][nj][r];
            }
}

// ---- coarse + detail GEMM in one launch, grid (6,13,8) = 624 blocks.
// Bijective chunked XCD swizzle (624 = 8 x 78): each XCD owns 6 complete (nt,z)
// groups of 13 mt-blocks sharing one W-slice -> L2 W reuse (T1).
__global__ __launch_bounds__(256) void gemmcd_k(const unsigned short* __restrict__ Ac,
                                                const unsigned short* __restrict__ Wc,
                                                const unsigned short* __restrict__ Wd,
                                                const int* __restrict__ topk,
                                                float* __restrict__ partC,
                                                float* __restrict__ partD){
    __shared__ __align__(16) unsigned short As[64*64];
    __shared__ __align__(16) unsigned short Bs[128*64];
    const int lid = blockIdx.x + 6*(blockIdx.y + 13*blockIdx.z);  // 0..623
    const int swz = (lid&7)*78 + (lid>>3);                        // bijective
    const int mt  = swz % 13;
    const int g   = swz / 13;
    const int nt  = g % 6;
    const int z   = g / 6;
    if (mt < 9)
        gemm_body<0,2048,576>(Ac, Wc, nullptr, partC, As, Bs, nt, mt, z);
    else
        gemm_body<1,512,256>(Ac, Wd, topk, partD, As, Bs, nt, mt-9, z);
}

// ---- merge GEMM (unchanged structure)
__global__ __launch_bounds__(256) void gemmm_k(const unsigned short* __restrict__ A,
                                               const unsigned short* __restrict__ W,
                                               float* __restrict__ part){
    __shared__ __align__(16) unsigned short As[64*64];
    __shared__ __align__(16) unsigned short Bs[128*64];
    gemm_body<2,768,1024>(A, W, nullptr, part, As, Bs, blockIdx.x, blockIdx.y, blockIdx.z);
}

// ---- merged per-batch reduction: coarse (f32 out) + detail (bf16 out), both z=8
__global__ __launch_bounds__(256) void reduceboth_k(const float* __restrict__ partC,
                                                    const float* __restrict__ partD,
                                                    const float* __restrict__ cb,
                                                    const float* __restrict__ db,
                                                    float* __restrict__ outC,
                                                    unsigned short* __restrict__ outD){
    int bid = blockIdx.x;
    if (bid < 1728){
        int idx = bid*256 + threadIdx.x;          // 0..442367
        int col = idx % 768;
        float s = cb[col];
        #pragma unroll
        for (int i=0;i<8;i++) s += partC[(size_t)i*442368 + idx];
        outC[idx] = s;
    } else {
        int idx = (bid-1728)*256 + threadIdx.x;   // 0..196607
        int col = idx % 768;
        float s = db[col];
        #pragma unroll
        for (int i=0;i<8;i++) s += partD[(size_t)i*196608 + idx];
        outD[idx] = f2bf(s);
    }
}

// ---- final merge reduction: sum K-split partials + bias -> f32
__global__ __launch_bounds__(256) void reduce_k(const float* __restrict__ partials,
                                                const float* __restrict__ bias,
                                                float* __restrict__ outp,
                                                int MTOT, int NSPLIT){
    int idx = blockIdx.x*256 + threadIdx.x;
    int col = idx % 768;
    float s = bias[col];
    for (int i=0;i<NSPLIT;i++) s += partials[(size_t)i*MTOT*768 + idx];
    outp[idx] = s;
}

// ---- top-64 of 576 via rank counting; jax tie-break (lower idx first), one shot
__global__ __launch_bounds__(576) void topk_k(const float* __restrict__ scores,
                                              int* __restrict__ topk,
                                              float* __restrict__ outf){
    __shared__ float s[576];
    int t = threadIdx.x;
    s[t] = scores[t];
    __syncthreads();
    float v = s[t];
    int cnt = 0;
    for (int j=0;j<576;j++){
        float u = s[j];
        cnt += (u > v) || (u == v && j < t);
    }
    if (cnt < 64){ topk[cnt] = t; outf[cnt] = (float)t; }
}

extern "C" void kernel_launch(void* const* d_in, const int* in_sizes, int n_in,
                              void* d_out, int out_size, void* d_ws, size_t ws_size,
                              hipStream_t stream){
    const float* x       = (const float*)d_in[0];
    const float* conv1_w = (const float*)d_in[1];
    const float* bn1_g   = (const float*)d_in[2];
    const float* bn1_b   = (const float*)d_in[3];
    const float* bn1_m   = (const float*)d_in[4];
    const float* bn1_v   = (const float*)d_in[5];
    const float* conv2_w = (const float*)d_in[6];
    const float* bn2_g   = (const float*)d_in[7];
    const float* bn2_b   = (const float*)d_in[8];
    const float* bn2_m   = (const float*)d_in[9];
    const float* bn2_v   = (const float*)d_in[10];
    const float* coarse_w= (const float*)d_in[11];
    const float* coarse_b= (const float*)d_in[12];
    const float* detail_w= (const float*)d_in[13];
    const float* detail_b= (const float*)d_in[14];
    const float* merge_w = (const float*)d_in[15];
    const float* merge_b = (const float*)d_in[16];
    float* out = (float*)d_out;

    // ---- workspace layout (float units); ~166 MB ----
    float* wsp  = (float*)d_ws;
    unsigned short* f1hi = (unsigned short*)wsp;         // 9,535,744 bf16 (386*386*64)
    unsigned short* f1lo = f1hi + 9535744;               // 9,535,744 bf16
    float* parts = wsp + 9535744;                        // 1,179,648 f32 (slot 9.4M)
    float* bnp  = parts + 9437184;                       // 256
    float* scores = bnp + 256;                           // 9,216
    int*   topk = (int*)(scores + 9216);                 // 1,024
    unsigned short* B2hi = (unsigned short*)(topk + 1024);   // 36,864 bf16
    unsigned short* B2lo = B2hi + 36864;                     // 36,864 bf16
    unsigned short* Wc16 = B2lo + 36864;                     // 12,582,912 bf16
    unsigned short* Wd16 = Wc16 + 12582912;                  // 3,145,728 bf16
    unsigned short* Wm16 = Wd16 + 3145728;                   // 2,359,296 bf16
    unsigned short* Ac16 = Wm16 + 2359296;                   // 9,437,184 bf16
    unsigned short* dp16 = Ac16 + 9437184;                   // 3,145,728 bf16
    float* part = (float*)(dp16 + 3145728);                  // coarse partials (z=8)
    float* partD = part + 3538944;                           // detail partials (z=8)

    if (ws_size < (size_t)171000000) return;   // graceful fail if ws too small

    const int DETAIL_OFF = 16*576*768;            // 7077888
    const int IDX_OFF    = DETAIL_OFF + 16*64*768;// 7864320

    prep_k<<<194,256,0,stream>>>(bn1_g,bn1_b,bn1_m,bn1_v, bn2_g,bn2_b,bn2_m,bn2_v,
                                 conv2_w, bnp, B2hi, B2lo, f1hi, f1lo);
    cvt3_k<<<70656,256,0,stream>>>(coarse_w, detail_w, merge_w, Wc16, Wd16, Wm16);

    for (int b = 0; b < 16; b++){
        conv1_k<<<2304,512,0,stream>>>(x + (size_t)b*442368, conv1_w, bnp, f1hi, f1lo);
        conv2_mfma_k<<<1024,192,0,stream>>>(f1hi, f1lo, B2hi, B2lo, bnp+128, bnp+192,
                                            Ac16, parts);
        score_k<<<576,64,0,stream>>>(parts, scores + b*576);
        topk_k<<<1,576,0,stream>>>(scores + b*576, topk + b*64, out + IDX_OFF + b*64);
        // coarse (z=8 KL=2048) + detail (z=8 KL=512) in one launch, XCD-chunked
        gemmcd_k<<<dim3(6,13,8),256,0,stream>>>(Ac16, Wc16, Wd16, topk + b*64,
                                                part, partD);
        // merged reduction: coarse f32 -> out, detail bf16 -> dp16
        reduceboth_k<<<2496,256,0,stream>>>(part, partD, coarse_b, detail_b,
                                            out + (size_t)b*442368,
                                            dp16 + (size_t)b*196608);
    }

    // merge over all batches: M=1024, K=3072
    gemmm_k<<<dim3(6,16,4),256,0,stream>>>(dp16, Wm16, part);
    reduce_k<<<3072,256,0,stream>>>(part, merge_b, out + DETAIL_OFF, 1024, 4);
}